// Round 3
// baseline (748.563 us; speedup 1.0000x reference)
//
#include <hip/hip_runtime.h>
#include <cfloat>

typedef _Float16 half8 __attribute__((ext_vector_type(8)));
typedef float    f32x4 __attribute__((ext_vector_type(4)));

#define N_ROWS 65536
#define DIM    256
#define KCODES 4096

// ---------------- workspace layout (bytes) ----------------
// packed fragment tiles: tile = 16 rows x 32 k = 512 f16 = 1KB, lane-ordered
//   elem index in tile = (q*16 + n)*8 + j   (n=row%16, q=(k%32)/8, j=k%8)
// bp[sl][ct][hl][1KB]  sl=k/32 (8), ct=c/16 (256), hl=0 hi / 1 lo
// ap[sl][rt][hl][1KB]  rt=row/16 (4096)
#define WS_BP   0ULL
#define WS_AP   4194304ULL
#define WS_CSQ  71303168ULL
#define WS_XSQ  71319552ULL
#define WS_PD   71581696ULL
#define WS_PI   72630272ULL
#define WS_NEED 73678848ULL

__device__ __forceinline__ void gld16(const void* g, void* l) {
    __builtin_amdgcn_global_load_lds(
        (const __attribute__((address_space(1))) unsigned int*)g,
        (__attribute__((address_space(3))) unsigned int*)l, 16, 0, 0);
}

// ---- Prologue A: codebook -> csq (k-ascending fmaf, matched ref) + packed f16 hi/lo (x64) ----
__global__ void prep_codes(const float* __restrict__ cb, float* __restrict__ csq,
                           _Float16* __restrict__ bp) {
    __shared__ float As[16 * DIM];   // 16 code rows
    const int t = threadIdx.x, ct = blockIdx.x;
    #pragma unroll
    for (int p = 0; p < 4; ++p)
        *(float4*)&As[p * 1024 + t * 4] = *(const float4*)&cb[(size_t)ct * 16 * DIM + p * 1024 + t * 4];
    __syncthreads();
    if (t < 16) {   // exact round-2 csq recipe: single fp32 fmaf chain, k ascending
        float s = 0.f;
        const float* r = &As[t * DIM];
        for (int k = 0; k < DIM; ++k) s = fmaf(r[k], r[k], s);
        csq[ct * 16 + t] = s;
    }
    // pack: 32 octets x 16 rows = 512 tasks
    for (int u = t; u < 512; u += 256) {
        const int o = u >> 4, n = u & 15, sl = o >> 2, q = o & 3;
        const float* vp = &As[n * DIM + o * 8];
        half8 h, l;
        #pragma unroll
        for (int j = 0; j < 8; ++j) {
            float v = vp[j] * 64.f;                    // x64: keeps lo out of f16 subnormals
            _Float16 hh = (_Float16)v;
            h[j] = hh; l[j] = (_Float16)(v - (float)hh);
        }
        size_t base = (((size_t)sl * 256 + ct) * 2) * 1024 + (size_t)((q * 16 + n) * 8) * 2;
        *(half8*)((char*)bp + base)        = h;
        *(half8*)((char*)bp + base + 1024) = l;
    }
}

// ---- Prologue B: x -> xsq (fp64, matched ref) + packed f16 hi/lo (unscaled) ----
__global__ void prep_x(const float* __restrict__ x, float* __restrict__ xsq,
                       _Float16* __restrict__ ap) {
    __shared__ float  As[16 * DIM];
    __shared__ double dtmp[64];
    const int t = threadIdx.x, rt = blockIdx.x;
    #pragma unroll
    for (int p = 0; p < 4; ++p)
        *(float4*)&As[p * 1024 + t * 4] = *(const float4*)&x[(size_t)rt * 16 * DIM + p * 1024 + t * 4];
    __syncthreads();
    if (t < 64) {
        int r = t >> 2, part = t & 3;
        const float* apx = &As[r * DIM + 64 * part];
        double s = 0.0;
        for (int k = 0; k < 64; ++k) { double v = (double)apx[k]; s = fma(v, v, s); }
        dtmp[t] = s;
    }
    __syncthreads();
    if (t < 16)
        xsq[rt * 16 + t] = (float)((dtmp[4*t] + dtmp[4*t+1]) + (dtmp[4*t+2] + dtmp[4*t+3]));
    for (int u = t; u < 512; u += 256) {
        const int o = u >> 4, n = u & 15, sl = o >> 2, q = o & 3;
        const float* vp = &As[n * DIM + o * 8];
        half8 h, l;
        #pragma unroll
        for (int j = 0; j < 8; ++j) {
            float v = vp[j];
            _Float16 hh = (_Float16)v;
            h[j] = hh; l[j] = (_Float16)(v - (float)hh);
        }
        size_t base = (((size_t)sl * 4096 + rt) * 2) * 1024 + (size_t)((q * 16 + n) * 8) * 2;
        *(half8*)((char*)ap + base)        = h;
        *(half8*)((char*)ap + base + 1024) = l;
    }
}

// ---- Main: 3-split f16 MFMA GEMM + fused argmin over a column quarter ----
// grid 2048 = 512 rowblocks x 4 col quarters; block 256 = 4 waves (wy,wx in 2x2)
__global__ __launch_bounds__(256, 3)
void vq_main(const _Float16* __restrict__ ap, const _Float16* __restrict__ bp,
             const float* __restrict__ csq, const float* __restrict__ xsq,
             float* __restrict__ pdist, int* __restrict__ pidx) {
    __shared__ _Float16 sA[8192];   // 16KB: 8 row-tiles x {hi,lo} x 1KB
    __shared__ _Float16 sB[8192];   // 16KB: 8 col-tiles x {hi,lo} x 1KB

    const int t = threadIdx.x, lane = t & 63, wave = t >> 6;
    const int wy = wave >> 1, wx = wave & 1;
    const int m = lane & 15, q = lane >> 4;
    const int rowblock = blockIdx.x >> 2, colq = blockIdx.x & 3;
    const int n0 = rowblock * 128, rt0 = rowblock * 8;
    const char* apb = (const char*)ap;
    const char* bpb = (const char*)bp;
    const int wofs = wave * 1024;      // wave-uniform LDS stage base

    float xsq_r[16];
    #pragma unroll
    for (int s = 0; s < 16; ++s)
        xsq_r[s] = xsq[n0 + 64 * wy + 16 * (s >> 2) + 4 * q + (s & 3)];

    float best[16]; int bidx[16];
    #pragma unroll
    for (int s = 0; s < 16; ++s) { best[s] = FLT_MAX; bidx[s] = 0; }

    for (int chunk = 0; chunk < 8; ++chunk) {
        const int c0 = colq * 1024 + chunk * 128;
        const int ct0 = c0 >> 4;
        float csq_c[4];
        #pragma unroll
        for (int tc = 0; tc < 4; ++tc) csq_c[tc] = csq[c0 + 64 * wx + 16 * tc + m];

        f32x4 acc[4][4];
        #pragma unroll
        for (int tr = 0; tr < 4; ++tr)
            #pragma unroll
            for (int tc = 0; tc < 4; ++tc) acc[tr][tc] = (f32x4){0.f, 0.f, 0.f, 0.f};

        for (int sl = 0; sl < 8; ++sl) {
            __syncthreads();   // prior slice fully consumed by all waves
            const size_t abase = (((size_t)sl * 4096 + rt0) * 2) * 1024;
            const size_t bbase = (((size_t)sl * 256 + ct0) * 2) * 1024;
            #pragma unroll
            for (int i = 0; i < 4; ++i) {
                gld16(apb + abase + i * 4096 + t * 16, (char*)sA + i * 4096 + wofs);
                gld16(bpb + bbase + i * 4096 + t * 16, (char*)sB + i * 4096 + wofs);
            }
            __syncthreads();   // DMA drained (compiler emits vmcnt(0) before barrier)

            half8 bH[4], bL[4];
            #pragma unroll
            for (int tc = 0; tc < 4; ++tc) {
                const int ctl = 4 * wx + tc;
                bH[tc] = *(const half8*)&sB[ctl * 1024 + lane * 8];
                bL[tc] = *(const half8*)&sB[ctl * 1024 + 512 + lane * 8];
            }
            #pragma unroll
            for (int tr = 0; tr < 4; ++tr) {
                const int rtl = 4 * wy + tr;
                half8 aH = *(const half8*)&sA[rtl * 1024 + lane * 8];
                half8 aL = *(const half8*)&sA[rtl * 1024 + 512 + lane * 8];
                #pragma unroll
                for (int tc = 0; tc < 4; ++tc)
                    acc[tr][tc] = __builtin_amdgcn_mfma_f32_16x16x32_f16(aH, bH[tc], acc[tr][tc], 0, 0, 0);
                #pragma unroll
                for (int tc = 0; tc < 4; ++tc)
                    acc[tr][tc] = __builtin_amdgcn_mfma_f32_16x16x32_f16(aH, bL[tc], acc[tr][tc], 0, 0, 0);
                #pragma unroll
                for (int tc = 0; tc < 4; ++tc)
                    acc[tr][tc] = __builtin_amdgcn_mfma_f32_16x16x32_f16(aL, bH[tc], acc[tr][tc], 0, 0, 0);
            }
        }
        // epilogue: dist = (xsq - 2*dot) + csq, exact reference rounding; strict < keeps lowest c
        #pragma unroll
        for (int tc = 0; tc < 4; ++tc) {
            const int c = c0 + 64 * wx + 16 * tc + m;
            #pragma unroll
            for (int tr = 0; tr < 4; ++tr) {
                #pragma unroll
                for (int e = 0; e < 4; ++e) {
                    float dot = acc[tr][tc][e] * 0.015625f;   // exact /64
                    float d = fmaf(-2.f, dot, xsq_r[tr * 4 + e]) + csq_c[tc];
                    const int s = tr * 4 + e;
                    if (d < best[s]) { best[s] = d; bidx[s] = c; }
                }
            }
        }
    }

    // reduce over the 16 column-lanes (xor bits 0..3 keep q fixed -> same rows)
    #pragma unroll
    for (int s = 0; s < 16; ++s) {
        float v = best[s]; int idx = bidx[s];
        #pragma unroll
        for (int off = 1; off < 16; off <<= 1) {
            float v2 = __shfl_xor(v, off);
            int   i2 = __shfl_xor(idx, off);
            if (v2 < v || (v2 == v && i2 < idx)) { v = v2; idx = i2; }
        }
        best[s] = v; bidx[s] = idx;
    }
    __syncthreads();
    float* rb = (float*)sA;
    int*   ri = (int*)((char*)sA + 1024);
    {
        const int s = m;   // lane -> slot bijection within wave
        const int row_local = 64 * wy + 16 * (s >> 2) + 4 * q + (s & 3);
        rb[row_local * 2 + wx] = best[s];
        ri[row_local * 2 + wx] = bidx[s];
    }
    __syncthreads();
    if (t < 128) {
        float d0 = rb[2 * t], d1 = rb[2 * t + 1];
        int   i0 = ri[2 * t], i1 = ri[2 * t + 1];
        bool sw = (d1 < d0) || (d1 == d0 && i1 < i0);
        pdist[colq * N_ROWS + n0 + t] = sw ? d1 : d0;
        pidx [colq * N_ROWS + n0 + t] = sw ? i1 : i0;
    }
}

// ---- Merge 4 column-quarter candidates + gather winners ----
__global__ void merge_gather(const float* __restrict__ cb, const float* __restrict__ pdist,
                             const int* __restrict__ pidx, float* __restrict__ out_q,
                             float* __restrict__ out_idx) {
    __shared__ int widx[64];
    const int t = threadIdx.x, r0 = blockIdx.x * 64;
    if (t < 64) {
        const int r = r0 + t;
        float d = pdist[r]; int w = pidx[r];
        #pragma unroll
        for (int qy = 1; qy < 4; ++qy) {
            float dq = pdist[qy * N_ROWS + r]; int iq = pidx[qy * N_ROWS + r];
            if (dq < d) { d = dq; w = iq; }    // strict <: lower quarter (lower idx) wins ties
        }
        widx[t] = w;
        out_idx[r] = (float)w;
    }
    __syncthreads();
    const int l4 = t & 63, rg = t >> 6;
    #pragma unroll
    for (int i = 0; i < 16; ++i) {
        const int rl = rg + 4 * i;
        *(float4*)&out_q[(size_t)(r0 + rl) * DIM + l4 * 4] =
            *(const float4*)&cb[(size_t)widx[rl] * DIM + l4 * 4];
    }
}

// ================= fallback (ws too small): round-1 self-contained fp32 kernel =================
__global__ __launch_bounds__(256, 2)
void vq_argmin_fallback(const float* __restrict__ x, const float* __restrict__ cb,
                        float* __restrict__ out_q, float* __restrict__ out_idx) {
    __shared__ float As[32 * DIM];
    __shared__ float Bs[32 * 256];
    const int t = threadIdx.x;
    const int tx = t & 63, ty = t >> 6;
    const int n0 = blockIdx.x * 32;
    #pragma unroll
    for (int i = 0; i < 8; ++i) {
        int r = 4 * i + (t >> 6), d4 = (t & 63) * 4;
        *(float4*)&As[r * DIM + d4] = *(const float4*)&x[(size_t)(n0 + r) * DIM + d4];
    }
    __syncthreads();
    double* dtmp = (double*)Bs;
    if (t < 128) {
        int r = t >> 2, part = t & 3;
        const float* ap = &As[r * DIM + 64 * part];
        double s = 0.0;
        for (int k = 0; k < 64; ++k) { double v = (double)ap[k]; s = fma(v, v, s); }
        dtmp[t] = s;
    }
    __syncthreads();
    float* xf = (float*)Bs + 512;
    if (t < 32) xf[t] = (float)((dtmp[4*t] + dtmp[4*t+1]) + (dtmp[4*t+2] + dtmp[4*t+3]));
    __syncthreads();
    float xsq_r[8];
    #pragma unroll
    for (int j = 0; j < 8; ++j) xsq_r[j] = xf[8 * ty + j];
    float best[8]; int bidx[8];
    #pragma unroll
    for (int j = 0; j < 8; ++j) { best[j] = FLT_MAX; bidx[j] = 0; }
    for (int chunk = 0; chunk < 16; ++chunk) {
        const int c0 = chunk * 256;
        float acc[8][4];
        #pragma unroll
        for (int j = 0; j < 8; ++j) { acc[j][0]=0; acc[j][1]=0; acc[j][2]=0; acc[j][3]=0; }
        float csq[4] = {0,0,0,0};
        for (int sl = 0; sl < 8; ++sl) {
            const int ks = sl * 32;
            __syncthreads();
            const int cl = t & 31, qq = t >> 5;
            #pragma unroll
            for (int i = 0; i < 8; ++i) {
                int c_loc = 32 * i + cl;
                float4 v = *(const float4*)&cb[(size_t)(c0 + c_loc) * DIM + ks + 4 * qq];
                int kk = 4 * qq;
                Bs[(kk+0) * 256 + ((c_loc + 4*(kk+0)) & 255)] = v.x;
                Bs[(kk+1) * 256 + ((c_loc + 4*(kk+1)) & 255)] = v.y;
                Bs[(kk+2) * 256 + ((c_loc + 4*(kk+2)) & 255)] = v.z;
                Bs[(kk+3) * 256 + ((c_loc + 4*(kk+3)) & 255)] = v.w;
            }
            __syncthreads();
            #pragma unroll
            for (int kb = 0; kb < 8; ++kb) {
                float4 a[8];
                #pragma unroll
                for (int j = 0; j < 8; ++j)
                    a[j] = *(const float4*)&As[(8 * ty + j) * DIM + ks + 4 * kb];
                #pragma unroll
                for (int u = 0; u < 4; ++u) {
                    int kk = 4 * kb + u;
                    float4 b = *(const float4*)&Bs[kk * 256 + ((4 * tx + 4 * kk) & 255)];
                    csq[0] = fmaf(b.x, b.x, csq[0]); csq[1] = fmaf(b.y, b.y, csq[1]);
                    csq[2] = fmaf(b.z, b.z, csq[2]); csq[3] = fmaf(b.w, b.w, csq[3]);
                    #pragma unroll
                    for (int j = 0; j < 8; ++j) {
                        float av = (u==0)?a[j].x:(u==1)?a[j].y:(u==2)?a[j].z:a[j].w;
                        acc[j][0] = fmaf(av, b.x, acc[j][0]); acc[j][1] = fmaf(av, b.y, acc[j][1]);
                        acc[j][2] = fmaf(av, b.z, acc[j][2]); acc[j][3] = fmaf(av, b.w, acc[j][3]);
                    }
                }
            }
        }
        #pragma unroll
        for (int j = 0; j < 8; ++j)
            #pragma unroll
            for (int cc = 0; cc < 4; ++cc) {
                float d = fmaf(-2.f, acc[j][cc], xsq_r[j]) + csq[cc];
                int c = c0 + 4 * tx + cc;
                if (d < best[j]) { best[j] = d; bidx[j] = c; }
            }
    }
    __syncthreads();
    int* idxs = (int*)Bs;
    #pragma unroll
    for (int j = 0; j < 8; ++j) {
        float v = best[j]; int idx = bidx[j];
        #pragma unroll
        for (int off = 1; off < 64; off <<= 1) {
            float v2 = __shfl_xor(v, off);
            int  i2 = __shfl_xor(idx, off);
            if (v2 < v || (v2 == v && i2 < idx)) { v = v2; idx = i2; }
        }
        if (tx == 0) idxs[8 * ty + j] = idx;
    }
    __syncthreads();
    if (t < 32) out_idx[n0 + t] = (float)idxs[t];
    #pragma unroll
    for (int i = 0; i < 8; ++i) {
        int r = 4 * i + (t >> 6), d4 = (t & 63) * 4;
        *(float4*)&out_q[(size_t)(n0 + r) * DIM + d4] =
            *(const float4*)&cb[(size_t)idxs[r] * DIM + d4];
    }
}

extern "C" void kernel_launch(void* const* d_in, const int* in_sizes, int n_in,
                              void* d_out, int out_size, void* d_ws, size_t ws_size,
                              hipStream_t stream) {
    const float* x  = (const float*)d_in[0];
    const float* cb = (const float*)d_in[1];
    float* out_q   = (float*)d_out;
    float* out_idx = (float*)d_out + (size_t)N_ROWS * DIM;

    if (ws_size < WS_NEED) {   // safety net: self-contained fp32 path
        vq_argmin_fallback<<<N_ROWS / 32, 256, 0, stream>>>(x, cb, out_q, out_idx);
        return;
    }
    _Float16* bpp = (_Float16*)((char*)d_ws + WS_BP);
    _Float16* app = (_Float16*)((char*)d_ws + WS_AP);
    float* csq   = (float*)((char*)d_ws + WS_CSQ);
    float* xsq   = (float*)((char*)d_ws + WS_XSQ);
    float* pdist = (float*)((char*)d_ws + WS_PD);
    int*   pidx  = (int*)  ((char*)d_ws + WS_PI);

    prep_codes<<<KCODES / 16, 256, 0, stream>>>(cb, csq, bpp);
    prep_x<<<N_ROWS / 16, 256, 0, stream>>>(x, xsq, app);
    vq_main<<<(N_ROWS / 128) * 4, 256, 0, stream>>>(app, bpp, csq, xsq, pdist, pidx);
    merge_gather<<<N_ROWS / 64, 256, 0, stream>>>(cb, pdist, pidx, out_q, out_idx);
}

// Round 5
// 688.513 us; speedup vs baseline: 1.0872x; 1.0872x over previous
//
#include <hip/hip_runtime.h>
#include <cfloat>

typedef _Float16 half8  __attribute__((ext_vector_type(8)));
typedef float    f32x16 __attribute__((ext_vector_type(16)));

#define N_ROWS 65536
#define DIM    256
#define KCODES 4096

// ---------------- workspace layout (bytes) ----------------
// fragment tiles for 32x32x16: tile = 32 rows x 16 k = 512 f16 = 1KB
//   elem offset in tile = ((k>>3)*32 + m)*8 + (k&7)   (m=row%32, k=k%16)
// bp[sl16][ct][hl][1KB]  sl16=k/16 (16), ct=c/32 (128), hl=0 hi /1 lo (codes x64)
// ap[sl16][rt][hl][1KB]  rt=row/32 (2048)
// sizes: bp = 16*128*2*1KB = 4,194,304   ap = 16*2048*2*1KB = 67,108,864
#define WS_BP   0ULL
#define WS_AP   4194304ULL
#define WS_CSQ  71303168ULL   /* 4194304 + 67108864 */
#define WS_XSQ  71319552ULL   /* + 4096*4            */
#define WS_PD   71581696ULL   /* + 65536*4           */
#define WS_PI   72630272ULL   /* + 4*65536*4         */
#define WS_NEED 73678848ULL   /* + 4*65536*4         */

__device__ __forceinline__ void gld16(const void* g, void* l) {
    __builtin_amdgcn_global_load_lds(
        (const __attribute__((address_space(1))) unsigned int*)g,
        (__attribute__((address_space(3))) unsigned int*)l, 16, 0, 0);
}

// ---- Prologue A: codebook -> csq (k-ascending fmaf, matched ref) + packed f16 hi/lo (x64) ----
__global__ void prep_codes(const float* __restrict__ cb, float* __restrict__ csq,
                           _Float16* __restrict__ bp) {
    __shared__ float As[32 * DIM];   // 32 code rows
    const int t = threadIdx.x, ct = blockIdx.x;   // ct: 32-code tile, 0..127
    #pragma unroll
    for (int p = 0; p < 8; ++p)
        *(float4*)&As[p * 1024 + t * 4] = *(const float4*)&cb[(size_t)ct * 32 * DIM + p * 1024 + t * 4];
    __syncthreads();
    if (t < 32) {   // exact csq recipe: single fp32 fmaf chain, k ascending
        float s = 0.f;
        const float* r = &As[t * DIM];
        for (int k = 0; k < DIM; ++k) s = fmaf(r[k], r[k], s);
        csq[ct * 32 + t] = s;
    }
    #pragma unroll
    for (int i = 0; i < 4; ++i) {       // 1024 octets: (sl16, kh, m)
        const int u = t + 256 * i;
        const int sl = u >> 6, kh = (u >> 5) & 1, m = u & 31;
        const float* vp = &As[m * DIM + sl * 16 + kh * 8];
        half8 h, l;
        #pragma unroll
        for (int j = 0; j < 8; ++j) {
            float v = vp[j] * 64.f;
            _Float16 hh = (_Float16)v;
            h[j] = hh; l[j] = (_Float16)(v - (float)hh);
        }
        size_t tb = ((size_t)((sl * 128 + ct) * 2) << 10) + (size_t)(kh * 32 + m) * 16;
        *(half8*)((char*)bp + tb)        = h;
        *(half8*)((char*)bp + tb + 1024) = l;
    }
}

// ---- Prologue B: x -> xsq (fp64, matched ref) + packed f16 hi/lo (unscaled) ----
__global__ void prep_x(const float* __restrict__ x, float* __restrict__ xsq,
                       _Float16* __restrict__ ap) {
    __shared__ float  As[32 * DIM];
    __shared__ double dtmp[128];
    const int t = threadIdx.x, rt = blockIdx.x;   // rt: 32-row tile, 0..2047
    #pragma unroll
    for (int p = 0; p < 8; ++p)
        *(float4*)&As[p * 1024 + t * 4] = *(const float4*)&x[(size_t)rt * 32 * DIM + p * 1024 + t * 4];
    __syncthreads();
    if (t < 128) {
        int r = t >> 2, part = t & 3;
        const float* apx = &As[r * DIM + 64 * part];
        double s = 0.0;
        for (int k = 0; k < 64; ++k) { double v = (double)apx[k]; s = fma(v, v, s); }
        dtmp[t] = s;
    }
    __syncthreads();
    if (t < 32)
        xsq[rt * 32 + t] = (float)((dtmp[4*t] + dtmp[4*t+1]) + (dtmp[4*t+2] + dtmp[4*t+3]));
    #pragma unroll
    for (int i = 0; i < 4; ++i) {
        const int u = t + 256 * i;
        const int sl = u >> 6, kh = (u >> 5) & 1, m = u & 31;
        const float* vp = &As[m * DIM + sl * 16 + kh * 8];
        half8 h, l;
        #pragma unroll
        for (int j = 0; j < 8; ++j) {
            float v = vp[j];
            _Float16 hh = (_Float16)v;
            h[j] = hh; l[j] = (_Float16)(v - (float)hh);
        }
        size_t tb = ((size_t)((sl * 2048 + rt) * 2) << 10) + (size_t)(kh * 32 + m) * 16;
        *(half8*)((char*)ap + tb)        = h;
        *(half8*)((char*)ap + tb + 1024) = l;
    }
}

// ---- Main: 3-split f16 32x32 MFMA + fused argmin; dbuf LDS, 1 barrier/slice ----
// grid 2048 = 512 rowblocks x 4 col quarters; 4 waves (wy,wx 2x2), wave tile 64x64
__global__ __launch_bounds__(256, 2)
void vq_main(const _Float16* __restrict__ ap, const _Float16* __restrict__ bp,
             const float* __restrict__ csq, const float* __restrict__ xsq,
             float* __restrict__ pdist, int* __restrict__ pidx) {
    __shared__ _Float16 sA[2][8192];   // 2 x 16KB: [sl2][rtl(4)][hl] x 1KB tiles
    __shared__ _Float16 sB[2][8192];

    const int t = threadIdx.x, lane = t & 63, wave = t >> 6;
    const int wy = wave >> 1, wx = wave & 1;
    const int l31 = lane & 31, q5 = lane >> 5;
    const int rowblock = blockIdx.x >> 2, colq = blockIdx.x & 3;
    const int n0 = rowblock * 128, rt0 = rowblock * 4;
    const char* apc = (const char*)ap;
    const char* bpc = (const char*)bp;
    const bool isA = (wave < 2);
    const int  wsel = wave & 1;

    // stage one BK=32 slice (32 tiles: 16 A + 16 B; 8 gld16/wave, 1 tile each)
    auto stage = [&](int g, int bb) {
        const int sl = g & 7, chunk = g >> 3;
        const int ct0 = colq * 32 + chunk * 4;
        #pragma unroll
        for (int i = 0; i < 8; ++i) {
            const int tid = (wsel << 3) + i;           // 0..15
            const int sl2 = tid >> 3, i4 = (tid >> 1) & 3, hl = tid & 1;
            const int gsl = 2 * sl + sl2;
            if (isA) {
                size_t src = ((size_t)(((gsl * 2048) + rt0 + i4) * 2 + hl) << 10) + (size_t)lane * 16;
                gld16(apc + src, (char*)&sA[bb][0] + (((sl2 * 4 + i4) * 2 + hl) << 10));
            } else {
                size_t src = ((size_t)(((gsl * 128) + ct0 + i4) * 2 + hl) << 10) + (size_t)lane * 16;
                gld16(bpc + src, (char*)&sB[bb][0] + (((sl2 * 4 + i4) * 2 + hl) << 10));
            }
        }
    };

    float xsq_r[32];
    #pragma unroll
    for (int s = 0; s < 32; ++s) {
        const int reg = s & 15, tr = s >> 4;
        xsq_r[s] = xsq[n0 + 64 * wy + 32 * tr + (reg & 3) + 8 * (reg >> 2) + 4 * q5];
    }
    float best[32]; int bidx[32];
    #pragma unroll
    for (int s = 0; s < 32; ++s) { best[s] = FLT_MAX; bidx[s] = 0; }

    f32x16 acc[2][2];
    float csq_c[2];
    int c0 = 0;

    stage(0, 0);

    for (int g = 0; g < 64; ++g) {
        const int sl = g & 7, chunk = g >> 3, buf = g & 1;
        __syncthreads();                 // drains stage(g) (issued a full slice ago)
        if (g + 1 < 64) stage(g + 1, buf ^ 1);   // overwrites buf used at g-1 (reads done)
        if (sl == 0) {
            c0 = colq * 1024 + chunk * 128;
            csq_c[0] = csq[c0 + 64 * wx + l31];
            csq_c[1] = csq[c0 + 64 * wx + 32 + l31];
            #pragma unroll
            for (int tr = 0; tr < 2; ++tr)
                #pragma unroll
                for (int tc = 0; tc < 2; ++tc)
                    #pragma unroll
                    for (int e = 0; e < 16; ++e) acc[tr][tc][e] = 0.f;
        }
        #pragma unroll
        for (int sl2 = 0; sl2 < 2; ++sl2) {
            half8 aH[2], aL[2], bH[2], bL[2];
            #pragma unroll
            for (int tr = 0; tr < 2; ++tr) {
                const int base = ((sl2 * 4 + 2 * wy + tr) * 2) * 512 + lane * 8;
                aH[tr] = *(const half8*)&sA[buf][base];
                aL[tr] = *(const half8*)&sA[buf][base + 512];
            }
            #pragma unroll
            for (int tc = 0; tc < 2; ++tc) {
                const int base = ((sl2 * 4 + 2 * wx + tc) * 2) * 512 + lane * 8;
                bH[tc] = *(const half8*)&sB[buf][base];
                bL[tc] = *(const half8*)&sB[buf][base + 512];
            }
            #pragma unroll
            for (int tr = 0; tr < 2; ++tr)
                #pragma unroll
                for (int tc = 0; tc < 2; ++tc)
                    acc[tr][tc] = __builtin_amdgcn_mfma_f32_32x32x16_f16(aH[tr], bH[tc], acc[tr][tc], 0, 0, 0);
            #pragma unroll
            for (int tr = 0; tr < 2; ++tr)
                #pragma unroll
                for (int tc = 0; tc < 2; ++tc)
                    acc[tr][tc] = __builtin_amdgcn_mfma_f32_32x32x16_f16(aH[tr], bL[tc], acc[tr][tc], 0, 0, 0);
            #pragma unroll
            for (int tr = 0; tr < 2; ++tr)
                #pragma unroll
                for (int tc = 0; tc < 2; ++tc)
                    acc[tr][tc] = __builtin_amdgcn_mfma_f32_32x32x16_f16(aL[tr], bH[tc], acc[tr][tc], 0, 0, 0);
        }
        if (sl == 7) {   // chunk epilogue: exact reference rounding; strict < keeps lowest c
            #pragma unroll
            for (int tc = 0; tc < 2; ++tc) {
                const int c = c0 + 64 * wx + 32 * tc + l31;
                #pragma unroll
                for (int tr = 0; tr < 2; ++tr) {
                    #pragma unroll
                    for (int reg = 0; reg < 16; ++reg) {
                        const float dot = acc[tr][tc][reg] * 0.015625f;   // exact /64
                        const int s = tr * 16 + reg;
                        const float d = fmaf(-2.f, dot, xsq_r[s]) + csq_c[tc];
                        if (d < best[s]) { best[s] = d; bidx[s] = c; }
                    }
                }
            }
        }
    }

    // reduce each row over the 32 column-lanes (offsets 1..16 keep q5 fixed)
    __syncthreads();
    float* rb = (float*)&sA[0][0];
    int*   ri = (int*)&sA[0][512];
    #pragma unroll
    for (int s = 0; s < 32; ++s) {
        float v = best[s]; int idx = bidx[s];
        #pragma unroll
        for (int off = 1; off < 32; off <<= 1) {
            float v2 = __shfl_xor(v, off);
            int   i2 = __shfl_xor(idx, off);
            if (v2 < v || (v2 == v && i2 < idx)) { v = v2; idx = i2; }
        }
        if (l31 == 0) {
            const int reg = s & 15;
            const int row_local = 64 * wy + 32 * (s >> 4) + (reg & 3) + 8 * (reg >> 2) + 4 * q5;
            rb[row_local * 2 + wx] = v;
            ri[row_local * 2 + wx] = idx;
        }
    }
    __syncthreads();
    if (t < 128) {
        float d0 = rb[2 * t], d1 = rb[2 * t + 1];
        int   i0 = ri[2 * t], i1 = ri[2 * t + 1];
        bool sw = (d1 < d0) || (d1 == d0 && i1 < i0);
        pdist[colq * N_ROWS + n0 + t] = sw ? d1 : d0;
        pidx [colq * N_ROWS + n0 + t] = sw ? i1 : i0;
    }
}

// ---- Merge 4 column-quarter candidates + gather winners ----
__global__ void merge_gather(const float* __restrict__ cb, const float* __restrict__ pdist,
                             const int* __restrict__ pidx, float* __restrict__ out_q,
                             float* __restrict__ out_idx) {
    __shared__ int widx[64];
    const int t = threadIdx.x, r0 = blockIdx.x * 64;
    if (t < 64) {
        const int r = r0 + t;
        float d = pdist[r]; int w = pidx[r];
        #pragma unroll
        for (int qy = 1; qy < 4; ++qy) {
            float dq = pdist[qy * N_ROWS + r]; int iq = pidx[qy * N_ROWS + r];
            if (dq < d) { d = dq; w = iq; }    // strict <: lower quarter (lower idx) wins ties
        }
        widx[t] = w;
        out_idx[r] = (float)w;
    }
    __syncthreads();
    const int l4 = t & 63, rg = t >> 6;
    #pragma unroll
    for (int i = 0; i < 16; ++i) {
        const int rl = rg + 4 * i;
        *(float4*)&out_q[(size_t)(r0 + rl) * DIM + l4 * 4] =
            *(const float4*)&cb[(size_t)widx[rl] * DIM + l4 * 4];
    }
}

// ================= fallback (ws too small): round-1 self-contained fp32 kernel =================
__global__ __launch_bounds__(256, 2)
void vq_argmin_fallback(const float* __restrict__ x, const float* __restrict__ cb,
                        float* __restrict__ out_q, float* __restrict__ out_idx) {
    __shared__ float As[32 * DIM];
    __shared__ float Bs[32 * 256];
    const int t = threadIdx.x;
    const int tx = t & 63, ty = t >> 6;
    const int n0 = blockIdx.x * 32;
    #pragma unroll
    for (int i = 0; i < 8; ++i) {
        int r = 4 * i + (t >> 6), d4 = (t & 63) * 4;
        *(float4*)&As[r * DIM + d4] = *(const float4*)&x[(size_t)(n0 + r) * DIM + d4];
    }
    __syncthreads();
    double* dtmp = (double*)Bs;
    if (t < 128) {
        int r = t >> 2, part = t & 3;
        const float* ap = &As[r * DIM + 64 * part];
        double s = 0.0;
        for (int k = 0; k < 64; ++k) { double v = (double)ap[k]; s = fma(v, v, s); }
        dtmp[t] = s;
    }
    __syncthreads();
    float* xf = (float*)Bs + 512;
    if (t < 32) xf[t] = (float)((dtmp[4*t] + dtmp[4*t+1]) + (dtmp[4*t+2] + dtmp[4*t+3]));
    __syncthreads();
    float xsq_r[8];
    #pragma unroll
    for (int j = 0; j < 8; ++j) xsq_r[j] = xf[8 * ty + j];
    float best[8]; int bidx[8];
    #pragma unroll
    for (int j = 0; j < 8; ++j) { best[j] = FLT_MAX; bidx[j] = 0; }
    for (int chunk = 0; chunk < 16; ++chunk) {
        const int c0 = chunk * 256;
        float acc[8][4];
        #pragma unroll
        for (int j = 0; j < 8; ++j) { acc[j][0]=0; acc[j][1]=0; acc[j][2]=0; acc[j][3]=0; }
        float csq[4] = {0,0,0,0};
        for (int sl = 0; sl < 8; ++sl) {
            const int ks = sl * 32;
            __syncthreads();
            const int cl = t & 31, qq = t >> 5;
            #pragma unroll
            for (int i = 0; i < 8; ++i) {
                int c_loc = 32 * i + cl;
                float4 v = *(const float4*)&cb[(size_t)(c0 + c_loc) * DIM + ks + 4 * qq];
                int kk = 4 * qq;
                Bs[(kk+0) * 256 + ((c_loc + 4*(kk+0)) & 255)] = v.x;
                Bs[(kk+1) * 256 + ((c_loc + 4*(kk+1)) & 255)] = v.y;
                Bs[(kk+2) * 256 + ((c_loc + 4*(kk+2)) & 255)] = v.z;
                Bs[(kk+3) * 256 + ((c_loc + 4*(kk+3)) & 255)] = v.w;
            }
            __syncthreads();
            #pragma unroll
            for (int kb = 0; kb < 8; ++kb) {
                float4 a[8];
                #pragma unroll
                for (int j = 0; j < 8; ++j)
                    a[j] = *(const float4*)&As[(8 * ty + j) * DIM + ks + 4 * kb];
                #pragma unroll
                for (int u = 0; u < 4; ++u) {
                    int kk = 4 * kb + u;
                    float4 b = *(const float4*)&Bs[kk * 256 + ((4 * tx + 4 * kk) & 255)];
                    csq[0] = fmaf(b.x, b.x, csq[0]); csq[1] = fmaf(b.y, b.y, csq[1]);
                    csq[2] = fmaf(b.z, b.z, csq[2]); csq[3] = fmaf(b.w, b.w, csq[3]);
                    #pragma unroll
                    for (int j = 0; j < 8; ++j) {
                        float av = (u==0)?a[j].x:(u==1)?a[j].y:(u==2)?a[j].z:a[j].w;
                        acc[j][0] = fmaf(av, b.x, acc[j][0]); acc[j][1] = fmaf(av, b.y, acc[j][1]);
                        acc[j][2] = fmaf(av, b.z, acc[j][2]); acc[j][3] = fmaf(av, b.w, acc[j][3]);
                    }
                }
            }
        }
        #pragma unroll
        for (int j = 0; j < 8; ++j)
            #pragma unroll
            for (int cc = 0; cc < 4; ++cc) {
                float d = fmaf(-2.f, acc[j][cc], xsq_r[j]) + csq[cc];
                int c = c0 + 4 * tx + cc;
                if (d < best[j]) { best[j] = d; bidx[j] = c; }
            }
    }
    __syncthreads();
    int* idxs = (int*)Bs;
    #pragma unroll
    for (int j = 0; j < 8; ++j) {
        float v = best[j]; int idx = bidx[j];
        #pragma unroll
        for (int off = 1; off < 64; off <<= 1) {
            float v2 = __shfl_xor(v, off);
            int  i2 = __shfl_xor(idx, off);
            if (v2 < v || (v2 == v && i2 < idx)) { v = v2; idx = i2; }
        }
        if (tx == 0) idxs[8 * ty + j] = idx;
    }
    __syncthreads();
    if (t < 32) out_idx[n0 + t] = (float)idxs[t];
    #pragma unroll
    for (int i = 0; i < 8; ++i) {
        int r = 4 * i + (t >> 6), d4 = (t & 63) * 4;
        *(float4*)&out_q[(size_t)(n0 + r) * DIM + d4] =
            *(const float4*)&cb[(size_t)idxs[r] * DIM + d4];
    }
}

extern "C" void kernel_launch(void* const* d_in, const int* in_sizes, int n_in,
                              void* d_out, int out_size, void* d_ws, size_t ws_size,
                              hipStream_t stream) {
    const float* x  = (const float*)d_in[0];
    const float* cb = (const float*)d_in[1];
    float* out_q   = (float*)d_out;
    float* out_idx = (float*)d_out + (size_t)N_ROWS * DIM;

    if (ws_size < WS_NEED) {
        vq_argmin_fallback<<<N_ROWS / 32, 256, 0, stream>>>(x, cb, out_q, out_idx);
        return;
    }
    _Float16* bpp = (_Float16*)((char*)d_ws + WS_BP);
    _Float16* app = (_Float16*)((char*)d_ws + WS_AP);
    float* csq   = (float*)((char*)d_ws + WS_CSQ);
    float* xsq   = (float*)((char*)d_ws + WS_XSQ);
    float* pdist = (float*)((char*)d_ws + WS_PD);
    int*   pidx  = (int*)  ((char*)d_ws + WS_PI);

    prep_codes<<<KCODES / 32, 256, 0, stream>>>(cb, csq, bpp);
    prep_x<<<N_ROWS / 32, 256, 0, stream>>>(x, xsq, app);
    vq_main<<<(N_ROWS / 128) * 4, 256, 0, stream>>>(app, bpp, csq, xsq, pdist, pidx);
    merge_gather<<<N_ROWS / 64, 256, 0, stream>>>(cb, pdist, pidx, out_q, out_idx);
}